// Round 1
// baseline (950.535 us; speedup 1.0000x reference)
//
#include <hip/hip_runtime.h>

#define KK 27
#define MM 50000
#define NV 100000
#define CC 64
#define EPSV 1e-5f

// ---------------------------------------------------------------------------
// Sparse conv: for each pair p in offset k: out[outm[p]] += f[inm[p]] @ W[k]
// Block = (one k, chunk of pairs), 256 threads = 4 waves.
// lane d owns output channel d; W[k] column d lives in 64 VGPRs.
// Each wave stages 4 gathered rows into its own LDS tile [c][4] and does
// one broadcast float4 LDS read + 4 FMAs per c.
// ---------------------------------------------------------------------------
__global__ __launch_bounds__(256)
void conv_scatter(const float* __restrict__ f, const float* __restrict__ W,
                  const int* __restrict__ in_maps, const int* __restrict__ out_maps,
                  float* __restrict__ out, int ppb) {
    const int k    = blockIdx.y;
    const int lane = threadIdx.x & 63;
    const int wave = threadIdx.x >> 6;

    const float* Wk = W + k * CC * CC;
    float w[CC];
#pragma unroll
    for (int c = 0; c < CC; ++c) w[c] = Wk[c * CC + lane];

    __shared__ float lds_f[4][CC][4];   // [wave][channel][pair]

    const int* inm  = in_maps  + k * MM;
    const int* outm = out_maps + k * MM;
    const int pend = min(MM, (blockIdx.x + 1) * ppb);

    for (int p = blockIdx.x * ppb + wave * 4; p + 4 <= pend; p += 16) {
        int   outi[4];
        float msg[4] = {0.f, 0.f, 0.f, 0.f};
#pragma unroll
        for (int j = 0; j < 4; ++j) {
            const int ini = inm[p + j];
            outi[j] = outm[p + j];
            lds_f[wave][lane][j] = f[ini * CC + lane];   // coalesced 256B gather
        }
        // same-wave LDS write->read; compiler inserts lgkmcnt waits
#pragma unroll
        for (int c = 0; c < CC; ++c) {
            const float4 fv = *(const float4*)(&lds_f[wave][c][0]); // broadcast
            msg[0] = fmaf(fv.x, w[c], msg[0]);
            msg[1] = fmaf(fv.y, w[c], msg[1]);
            msg[2] = fmaf(fv.z, w[c], msg[2]);
            msg[3] = fmaf(fv.w, w[c], msg[3]);
        }
#pragma unroll
        for (int j = 0; j < 4; ++j)
            atomicAdd(&out[outi[j] * CC + lane], msg[j]);
    }
}

// ---------------------------------------------------------------------------
// BatchNorm stats: per-channel sum and sum-of-squares via block partials +
// one atomic per channel per block. stats[0..63]=sum, stats[64..127]=sumsq.
// ---------------------------------------------------------------------------
__global__ __launch_bounds__(256)
void bn_stats(const float* __restrict__ x, float* __restrict__ stats) {
    const int c  = threadIdx.x & 63;
    const int rg = threadIdx.x >> 6;
    float s = 0.f, ss = 0.f;
    for (int r = blockIdx.x * 4 + rg; r < NV; r += gridDim.x * 4) {
        const float v = x[r * CC + c];
        s += v;
        ss = fmaf(v, v, ss);
    }
    __shared__ float red[2][4][CC];
    red[0][rg][c] = s;
    red[1][rg][c] = ss;
    __syncthreads();
    if (threadIdx.x < CC) {
        const float ts  = red[0][0][c] + red[0][1][c] + red[0][2][c] + red[0][3][c];
        const float tss = red[1][0][c] + red[1][1][c] + red[1][2][c] + red[1][3][c];
        atomicAdd(&stats[c], ts);
        atomicAdd(&stats[CC + c], tss);
    }
}

// ---------------------------------------------------------------------------
// BN + ReLU, in place.  Channels of a float4 are fixed per-thread because the
// grid stride (in elements) is a multiple of 64.
// ---------------------------------------------------------------------------
__global__ __launch_bounds__(256)
void bn_relu_apply(float* __restrict__ x, const float* __restrict__ stats,
                   const float* __restrict__ gamma, const float* __restrict__ beta) {
    const int tid   = blockIdx.x * blockDim.x + threadIdx.x;
    const int total = NV * CC / 4;
    const int cbase = (tid * 4) & (CC - 1);
    float scale[4], shift[4];
#pragma unroll
    for (int j = 0; j < 4; ++j) {
        const int   c    = cbase + j;
        const float mu   = stats[c] * (1.f / NV);
        const float var  = fmaf(-mu, mu, stats[CC + c] * (1.f / NV));
        const float istd = rsqrtf(var + EPSV);
        scale[j] = gamma[c] * istd;
        shift[j] = fmaf(-mu, scale[j], beta[c]);
    }
    float4* x4 = (float4*)x;
    for (int i = tid; i < total; i += gridDim.x * blockDim.x) {
        float4 v = x4[i];
        v.x = fmaxf(fmaf(v.x, scale[0], shift[0]), 0.f);
        v.y = fmaxf(fmaf(v.y, scale[1], shift[1]), 0.f);
        v.z = fmaxf(fmaf(v.z, scale[2], shift[2]), 0.f);
        v.w = fmaxf(fmaf(v.w, scale[3], shift[3]), 0.f);
        x4[i] = v;
    }
}

// ---------------------------------------------------------------------------
// BN + residual + ReLU, x (=d_out) updated in place.
// ---------------------------------------------------------------------------
__global__ __launch_bounds__(256)
void bn_res_relu(float* __restrict__ x, const float* __restrict__ feat,
                 const float* __restrict__ stats,
                 const float* __restrict__ gamma, const float* __restrict__ beta) {
    const int tid   = blockIdx.x * blockDim.x + threadIdx.x;
    const int total = NV * CC / 4;
    const int cbase = (tid * 4) & (CC - 1);
    float scale[4], shift[4];
#pragma unroll
    for (int j = 0; j < 4; ++j) {
        const int   c    = cbase + j;
        const float mu   = stats[c] * (1.f / NV);
        const float var  = fmaf(-mu, mu, stats[CC + c] * (1.f / NV));
        const float istd = rsqrtf(var + EPSV);
        scale[j] = gamma[c] * istd;
        shift[j] = fmaf(-mu, scale[j], beta[c]);
    }
    float4*       x4 = (float4*)x;
    const float4* f4 = (const float4*)feat;
    for (int i = tid; i < total; i += gridDim.x * blockDim.x) {
        float4 v = x4[i];
        const float4 fr = f4[i];
        v.x = fmaxf(fmaf(v.x, scale[0], shift[0]) + fr.x, 0.f);
        v.y = fmaxf(fmaf(v.y, scale[1], shift[1]) + fr.y, 0.f);
        v.z = fmaxf(fmaf(v.z, scale[2], shift[2]) + fr.z, 0.f);
        v.w = fmaxf(fmaf(v.w, scale[3], shift[3]) + fr.w, 0.f);
        x4[i] = v;
    }
}

// ---------------------------------------------------------------------------
extern "C" void kernel_launch(void* const* d_in, const int* in_sizes, int n_in,
                              void* d_out, int out_size, void* d_ws, size_t ws_size,
                              hipStream_t stream) {
    const float* features = (const float*)d_in[0];
    const float* W1       = (const float*)d_in[1];
    const float* gamma1   = (const float*)d_in[2];
    const float* beta1    = (const float*)d_in[3];
    const float* W2       = (const float*)d_in[4];
    const float* gamma2   = (const float*)d_in[5];
    const float* beta2    = (const float*)d_in[6];
    const int*   in_maps  = (const int*)d_in[7];
    const int*   out_maps = (const int*)d_in[8];

    float* out   = (float*)d_out;
    float* tmp1  = (float*)d_ws;            // [NV*CC] conv1 accumulator / act1
    float* stats = tmp1 + (size_t)NV * CC;  // 256 floats: {sum1,sumsq1,sum2,sumsq2}

    // zero accumulators (ws and d_out are poisoned to 0xAA before every call)
    hipMemsetAsync(d_ws, 0, ((size_t)NV * CC + 256) * sizeof(float), stream);
    hipMemsetAsync(d_out, 0, (size_t)NV * CC * sizeof(float), stream);

    const int ppb = 1000;                   // 50 chunks x 1000 pairs = M exactly
    dim3 cgrid(MM / ppb, KK);

    conv_scatter<<<cgrid, 256, 0, stream>>>(features, W1, in_maps, out_maps, tmp1, ppb);
    bn_stats<<<256, 256, 0, stream>>>(tmp1, stats);
    bn_relu_apply<<<1024, 256, 0, stream>>>(tmp1, stats, gamma1, beta1);

    conv_scatter<<<cgrid, 256, 0, stream>>>(tmp1, W2, in_maps, out_maps, out, ppb);
    bn_stats<<<256, 256, 0, stream>>>(out, stats + 128);
    bn_res_relu<<<1024, 256, 0, stream>>>(out, features, stats + 128, gamma2, beta2);
}

// Round 4
// 786.165 us; speedup vs baseline: 1.2091x; 1.2091x over previous
//
#include <hip/hip_runtime.h>

#define KK 27
#define MM 50000
#define NV 100000
#define CC 64
#define EPSV 1e-5f

// ---------------------------------------------------------------------------
// Sparse conv: out[outm[p]] += f[inm[p]] @ W[k] for pairs p of offset k.
// Block = (chunk of pairs, k), 256 threads = 4 waves. Lane = output channel.
// W[k] staged to LDS once, then each lane's column held in 16 float4 VGPRs.
// Each wave processes 8 pairs/iter: gather 8 rows (per-lane element), stage
// to LDS [ch][8], broadcast-read float4 pairs, 512 FMAs, 8 coalesced atomics.
// ---------------------------------------------------------------------------
__global__ __launch_bounds__(256, 4)
void conv_scatter(const float* __restrict__ f, const float* __restrict__ W,
                  const int* __restrict__ in_maps, const int* __restrict__ out_maps,
                  float* __restrict__ out, int ppb) {
    const int k  = blockIdx.y;
    const int L  = threadIdx.x & 63;
    const int wv = threadIdx.x >> 6;

    __shared__ float Wlds[CC * CC];      // 16 KB
    __shared__ float lf[4][CC][8];       // 8 KB, per-wave staging

    // coalesced global->LDS stage of W[k]
    {
        const float4* Wg  = (const float4*)(W + (size_t)k * CC * CC);
        float4*       Wl4 = (float4*)Wlds;
#pragma unroll
        for (int i = 0; i < 4; ++i)
            Wl4[threadIdx.x + 256 * i] = Wg[threadIdx.x + 256 * i];
    }
    __syncthreads();

    // lane L's weight column W[c][L], c=0..63, in 16 named float4 regs
    float4 w[16];
#pragma unroll
    for (int i = 0; i < 16; ++i) {
        w[i].x = Wlds[(4 * i + 0) * CC + L];
        w[i].y = Wlds[(4 * i + 1) * CC + L];
        w[i].z = Wlds[(4 * i + 2) * CC + L];
        w[i].w = Wlds[(4 * i + 3) * CC + L];
    }

    const int* inm  = in_maps  + (size_t)k * MM;
    const int* outm = out_maps + (size_t)k * MM;
    const int pstart = blockIdx.x * ppb;
    const int pend   = min(MM, pstart + ppb);

    for (int p = pstart + wv * 8; p + 8 <= pend; p += 32) {
        const int4 ia = *(const int4*)(inm + p);
        const int4 ib = *(const int4*)(inm + p + 4);
        const int4 oa = *(const int4*)(outm + p);
        const int4 ob = *(const int4*)(outm + p + 4);

        float4 gA, gB;   // 8 independent gathers, coalesced 256B rows
        gA.x = f[(size_t)ia.x * CC + L];
        gA.y = f[(size_t)ia.y * CC + L];
        gA.z = f[(size_t)ia.z * CC + L];
        gA.w = f[(size_t)ia.w * CC + L];
        gB.x = f[(size_t)ib.x * CC + L];
        gB.y = f[(size_t)ib.y * CC + L];
        gB.z = f[(size_t)ib.z * CC + L];
        gB.w = f[(size_t)ib.w * CC + L];
        *(float4*)&lf[wv][L][0] = gA;
        *(float4*)&lf[wv][L][4] = gB;

        float msg[8] = {0.f, 0.f, 0.f, 0.f, 0.f, 0.f, 0.f, 0.f};
#pragma unroll
        for (int i = 0; i < 16; ++i) {
#pragma unroll
            for (int r = 0; r < 4; ++r) {
                const int c = 4 * i + r;
                const float4 fa = *(const float4*)&lf[wv][c][0];  // broadcast
                const float4 fb = *(const float4*)&lf[wv][c][4];  // broadcast
                const float wc = (r == 0) ? w[i].x : (r == 1) ? w[i].y
                               : (r == 2) ? w[i].z : w[i].w;
                msg[0] = fmaf(fa.x, wc, msg[0]);
                msg[1] = fmaf(fa.y, wc, msg[1]);
                msg[2] = fmaf(fa.z, wc, msg[2]);
                msg[3] = fmaf(fa.w, wc, msg[3]);
                msg[4] = fmaf(fb.x, wc, msg[4]);
                msg[5] = fmaf(fb.y, wc, msg[5]);
                msg[6] = fmaf(fb.z, wc, msg[6]);
                msg[7] = fmaf(fb.w, wc, msg[7]);
            }
        }
        atomicAdd(&out[(size_t)oa.x * CC + L], msg[0]);
        atomicAdd(&out[(size_t)oa.y * CC + L], msg[1]);
        atomicAdd(&out[(size_t)oa.z * CC + L], msg[2]);
        atomicAdd(&out[(size_t)oa.w * CC + L], msg[3]);
        atomicAdd(&out[(size_t)ob.x * CC + L], msg[4]);
        atomicAdd(&out[(size_t)ob.y * CC + L], msg[5]);
        atomicAdd(&out[(size_t)ob.z * CC + L], msg[6]);
        atomicAdd(&out[(size_t)ob.w * CC + L], msg[7]);
    }
}

// ---------------------------------------------------------------------------
// BatchNorm stats: per-channel sum / sumsq. stats[0..63]=sum, [64..127]=sumsq.
// ---------------------------------------------------------------------------
__global__ __launch_bounds__(256)
void bn_stats(const float* __restrict__ x, float* __restrict__ stats) {
    const int c  = threadIdx.x & 63;
    const int rg = threadIdx.x >> 6;
    float s = 0.f, ss = 0.f;
    for (int r = blockIdx.x * 4 + rg; r < NV; r += gridDim.x * 4) {
        const float v = x[(size_t)r * CC + c];
        s += v;
        ss = fmaf(v, v, ss);
    }
    __shared__ float red[2][4][CC];
    red[0][rg][c] = s;
    red[1][rg][c] = ss;
    __syncthreads();
    if (threadIdx.x < CC) {
        const float ts  = red[0][0][c] + red[0][1][c] + red[0][2][c] + red[0][3][c];
        const float tss = red[1][0][c] + red[1][1][c] + red[1][2][c] + red[1][3][c];
        atomicAdd(&stats[c], ts);
        atomicAdd(&stats[CC + c], tss);
    }
}

// ---------------------------------------------------------------------------
__global__ __launch_bounds__(256)
void bn_relu_apply(float* __restrict__ x, const float* __restrict__ stats,
                   const float* __restrict__ gamma, const float* __restrict__ beta) {
    const int tid   = blockIdx.x * blockDim.x + threadIdx.x;
    const int total = NV * CC / 4;
    const int cbase = (tid * 4) & (CC - 1);
    float scale[4], shift[4];
#pragma unroll
    for (int j = 0; j < 4; ++j) {
        const int   c    = cbase + j;
        const float mu   = stats[c] * (1.f / NV);
        const float var  = fmaf(-mu, mu, stats[CC + c] * (1.f / NV));
        const float istd = rsqrtf(var + EPSV);
        scale[j] = gamma[c] * istd;
        shift[j] = fmaf(-mu, scale[j], beta[c]);
    }
    float4* x4 = (float4*)x;
    for (int i = tid; i < total; i += gridDim.x * blockDim.x) {
        float4 v = x4[i];
        v.x = fmaxf(fmaf(v.x, scale[0], shift[0]), 0.f);
        v.y = fmaxf(fmaf(v.y, scale[1], shift[1]), 0.f);
        v.z = fmaxf(fmaf(v.z, scale[2], shift[2]), 0.f);
        v.w = fmaxf(fmaf(v.w, scale[3], shift[3]), 0.f);
        x4[i] = v;
    }
}

// ---------------------------------------------------------------------------
__global__ __launch_bounds__(256)
void bn_res_relu(float* __restrict__ x, const float* __restrict__ feat,
                 const float* __restrict__ stats,
                 const float* __restrict__ gamma, const float* __restrict__ beta) {
    const int tid   = blockIdx.x * blockDim.x + threadIdx.x;
    const int total = NV * CC / 4;
    const int cbase = (tid * 4) & (CC - 1);
    float scale[4], shift[4];
#pragma unroll
    for (int j = 0; j < 4; ++j) {
        const int   c    = cbase + j;
        const float mu   = stats[c] * (1.f / NV);
        const float var  = fmaf(-mu, mu, stats[CC + c] * (1.f / NV));
        const float istd = rsqrtf(var + EPSV);
        scale[j] = gamma[c] * istd;
        shift[j] = fmaf(-mu, scale[j], beta[c]);
    }
    float4*       x4 = (float4*)x;
    const float4* f4 = (const float4*)feat;
    for (int i = tid; i < total; i += gridDim.x * blockDim.x) {
        float4 v = x4[i];
        const float4 fr = f4[i];
        v.x = fmaxf(fmaf(v.x, scale[0], shift[0]) + fr.x, 0.f);
        v.y = fmaxf(fmaf(v.y, scale[1], shift[1]) + fr.y, 0.f);
        v.z = fmaxf(fmaf(v.z, scale[2], shift[2]) + fr.z, 0.f);
        v.w = fmaxf(fmaf(v.w, scale[3], shift[3]) + fr.w, 0.f);
        x4[i] = v;
    }
}

// ---------------------------------------------------------------------------
extern "C" void kernel_launch(void* const* d_in, const int* in_sizes, int n_in,
                              void* d_out, int out_size, void* d_ws, size_t ws_size,
                              hipStream_t stream) {
    const float* features = (const float*)d_in[0];
    const float* W1       = (const float*)d_in[1];
    const float* gamma1   = (const float*)d_in[2];
    const float* beta1    = (const float*)d_in[3];
    const float* W2       = (const float*)d_in[4];
    const float* gamma2   = (const float*)d_in[5];
    const float* beta2    = (const float*)d_in[6];
    const int*   in_maps  = (const int*)d_in[7];
    const int*   out_maps = (const int*)d_in[8];

    float* out   = (float*)d_out;
    float* tmp1  = (float*)d_ws;            // [NV*CC] conv1 accumulator / act1
    float* stats = tmp1 + (size_t)NV * CC;  // 256 floats: {sum1,sumsq1,sum2,sumsq2}

    hipMemsetAsync(d_ws, 0, ((size_t)NV * CC + 256) * sizeof(float), stream);
    hipMemsetAsync(d_out, 0, (size_t)NV * CC * sizeof(float), stream);

    const int ppb = 256;
    dim3 cgrid((MM + ppb - 1) / ppb, KK);   // 196 x 27 = 5292 blocks

    conv_scatter<<<cgrid, 256, 0, stream>>>(features, W1, in_maps, out_maps, tmp1, ppb);
    bn_stats<<<400, 256, 0, stream>>>(tmp1, stats);
    bn_relu_apply<<<1024, 256, 0, stream>>>(tmp1, stats, gamma1, beta1);

    conv_scatter<<<cgrid, 256, 0, stream>>>(tmp1, W2, in_maps, out_maps, out, ppb);
    bn_stats<<<400, 256, 0, stream>>>(out, stats + 128);
    bn_res_relu<<<1024, 256, 0, stream>>>(out, features, stats + 128, gamma2, beta2);
}

// Round 5
// 751.819 us; speedup vs baseline: 1.2643x; 1.0457x over previous
//
#include <hip/hip_runtime.h>

typedef __attribute__((ext_vector_type(8))) short bf16x8;
typedef __attribute__((ext_vector_type(4))) float f32x4;

#define KK 27
#define MM 50000
#define NV 100000
#define CC 64
#define EPSV 1e-5f
#define PPB 400

// Dekker-style f32 -> bf16 hi (truncate, exact residual) + bf16 lo (RNE).
__device__ inline void split2(float x, unsigned short& h, unsigned short& l) {
    const unsigned u  = __float_as_uint(x);
    const unsigned hb = u & 0xFFFF0000u;
    h = (unsigned short)(hb >> 16);
    const float r = x - __uint_as_float(hb);      // exact
    const unsigned v = __float_as_uint(r);
    l = (unsigned short)((v + 0x7FFFu + ((v >> 16) & 1u)) >> 16);
}

// ---------------------------------------------------------------------------
// features f32 [N][64] -> P [N][128] ushort: [0..63] bf16-hi, [64..127] bf16-lo
// ---------------------------------------------------------------------------
__global__ __launch_bounds__(256)
void split_planes(const float* __restrict__ x, unsigned short* __restrict__ P) {
    const int i = blockIdx.x * 256 + threadIdx.x;      // [0, NV*32)
    const int r = i >> 5, c2 = (i & 31) * 2;
    const float2 v = *(const float2*)(x + (size_t)r * CC + c2);
    unsigned short h0, l0, h1, l1;
    split2(v.x, h0, l0);
    split2(v.y, h1, l1);
    *(unsigned int*)(P + (size_t)r * 128 + c2)      = (unsigned)h0 | ((unsigned)h1 << 16);
    *(unsigned int*)(P + (size_t)r * 128 + 64 + c2) = (unsigned)l0 | ((unsigned)l1 << 16);
}

// ---------------------------------------------------------------------------
// MFMA sparse conv: out[outm[p]] += f[inm[p]] @ W[k], pairs tiled 16/wave.
// A = gathered bf16 hi/lo frags, B = W[k] hi/lo frags in regs,
// 24 x mfma_f32_16x16x32_bf16 per tile (3-product split, lo*lo dropped).
// C -> LDS transpose (stride 68, conflict-free) -> row-coalesced atomics.
// ---------------------------------------------------------------------------
#define MF(a, b, c) c = __builtin_amdgcn_mfma_f32_16x16x32_bf16(a, b, c, 0, 0, 0)

__global__ __launch_bounds__(256, 3)
void conv_mfma(const unsigned short* __restrict__ P, const float* __restrict__ W,
               const int* __restrict__ inm_all, const int* __restrict__ outm_all,
               float* __restrict__ out) {
    const int k   = blockIdx.y;
    const int L   = threadIdx.x & 63;
    const int wv  = threadIdx.x >> 6;
    const int g   = L >> 4;        // frag group 0..3
    const int c16 = L & 15;        // row-within-tile (A) / col-within-tile (B,C)

    __shared__ float lds[4352];    // 16KB W stage, then 4 x 1088 C-transpose

    // stage W[k] (f32, 16KB) coalesced
    {
        const float4* Wg  = (const float4*)(W + (size_t)k * CC * CC);
        float4*       Wl4 = (float4*)lds;
#pragma unroll
        for (int i = 0; i < 4; ++i)
            Wl4[threadIdx.x + 256 * i] = Wg[threadIdx.x + 256 * i];
    }
    __syncthreads();

    // B frags: lane holds W[(g*8+j)+32s][16t+c16], split hi/lo
    bf16x8 Wh[2][4], Wlo[2][4];
#pragma unroll
    for (int s = 0; s < 2; ++s)
#pragma unroll
        for (int t = 0; t < 4; ++t)
#pragma unroll
            for (int j = 0; j < 8; ++j) {
                const float w = lds[(g * 8 + j + 32 * s) * CC + 16 * t + c16];
                unsigned short h, lo;
                split2(w, h, lo);
                Wh[s][t][j]  = (short)h;
                Wlo[s][t][j] = (short)lo;
            }
    __syncthreads();   // everyone done with W in LDS before C-transpose reuse

    float* ldsC = lds + wv * 1088;     // 16 rows x stride 68

    const int* inm  = inm_all  + (size_t)k * MM;
    const int* outm = outm_all + (size_t)k * MM;
    const int pstart = blockIdx.x * PPB;
    const int pend   = min(MM, pstart + PPB);

    int base = pstart + wv * 16;
    if (base + 16 > pend) return;

    // prologue: A frags for first tile (gather 16 rows, lane reads its 16B slice)
    const unsigned short* rp = P + (size_t)inm[base + c16] * 128;
    bf16x8 ah0 = *(const bf16x8*)(rp +      g * 8);
    bf16x8 ah1 = *(const bf16x8*)(rp + 32 + g * 8);
    bf16x8 al0 = *(const bf16x8*)(rp + 64 + g * 8);
    bf16x8 al1 = *(const bf16x8*)(rp + 96 + g * 8);

    while (true) {
        const int  nbase = base + 64;
        const bool hasn  = (nbase + 16 <= pend);
        bf16x8 nh0, nh1, nl0, nl1;
        if (hasn) {  // prefetch next tile's A frags under this tile's MFMAs
            const unsigned short* np = P + (size_t)inm[nbase + c16] * 128;
            nh0 = *(const bf16x8*)(np +      g * 8);
            nh1 = *(const bf16x8*)(np + 32 + g * 8);
            nl0 = *(const bf16x8*)(np + 64 + g * 8);
            nl1 = *(const bf16x8*)(np + 96 + g * 8);
        }

        f32x4 acc0 = {0.f, 0.f, 0.f, 0.f}, acc1 = acc0, acc2 = acc0, acc3 = acc0;
        // Ah*Wh
        MF(ah0, Wh[0][0], acc0); MF(ah0, Wh[0][1], acc1); MF(ah0, Wh[0][2], acc2); MF(ah0, Wh[0][3], acc3);
        MF(ah1, Wh[1][0], acc0); MF(ah1, Wh[1][1], acc1); MF(ah1, Wh[1][2], acc2); MF(ah1, Wh[1][3], acc3);
        // Al*Wh
        MF(al0, Wh[0][0], acc0); MF(al0, Wh[0][1], acc1); MF(al0, Wh[0][2], acc2); MF(al0, Wh[0][3], acc3);
        MF(al1, Wh[1][0], acc0); MF(al1, Wh[1][1], acc1); MF(al1, Wh[1][2], acc2); MF(al1, Wh[1][3], acc3);
        // Ah*Wl
        MF(ah0, Wlo[0][0], acc0); MF(ah0, Wlo[0][1], acc1); MF(ah0, Wlo[0][2], acc2); MF(ah0, Wlo[0][3], acc3);
        MF(ah1, Wlo[1][0], acc0); MF(ah1, Wlo[1][1], acc1); MF(ah1, Wlo[1][2], acc2); MF(ah1, Wlo[1][3], acc3);

        // C frag [row=g*4+j][col=16t+c16] -> LDS (stride 68: conflict-free both ways)
#pragma unroll
        for (int j = 0; j < 4; ++j) {
            ldsC[(g * 4 + j) * 68 +      c16] = acc0[j];
            ldsC[(g * 4 + j) * 68 + 16 + c16] = acc1[j];
            ldsC[(g * 4 + j) * 68 + 32 + c16] = acc2[j];
            ldsC[(g * 4 + j) * 68 + 48 + c16] = acc3[j];
        }
        // row-coalesced scatter: lane L = channel, 256B per atomic instr
#pragma unroll
        for (int r = 0; r < 16; ++r) {
            const int orow = outm[base + r];
            atomicAdd(&out[(size_t)orow * CC + L], ldsC[r * 68 + L]);
        }

        if (!hasn) break;
        base = nbase;
        ah0 = nh0; ah1 = nh1; al0 = nl0; al1 = nl1;
    }
}

// ---------------------------------------------------------------------------
// BatchNorm stats: per-channel sum / sumsq. stats[0..63]=sum, [64..127]=sumsq.
// ---------------------------------------------------------------------------
__global__ __launch_bounds__(256)
void bn_stats(const float* __restrict__ x, float* __restrict__ stats) {
    const int c  = threadIdx.x & 63;
    const int rg = threadIdx.x >> 6;
    float s = 0.f, ss = 0.f;
    for (int r = blockIdx.x * 4 + rg; r < NV; r += gridDim.x * 4) {
        const float v = x[(size_t)r * CC + c];
        s += v;
        ss = fmaf(v, v, ss);
    }
    __shared__ float red[2][4][CC];
    red[0][rg][c] = s;
    red[1][rg][c] = ss;
    __syncthreads();
    if (threadIdx.x < CC) {
        const float ts  = red[0][0][c] + red[0][1][c] + red[0][2][c] + red[0][3][c];
        const float tss = red[1][0][c] + red[1][1][c] + red[1][2][c] + red[1][3][c];
        atomicAdd(&stats[c], ts);
        atomicAdd(&stats[CC + c], tss);
    }
}

// ---------------------------------------------------------------------------
// BN + ReLU + bf16 hi/lo split: x(f32) -> P planes (input for conv2).
// ---------------------------------------------------------------------------
__global__ __launch_bounds__(256)
void bn_relu_split(const float* __restrict__ x, const float* __restrict__ stats,
                   const float* __restrict__ gamma, const float* __restrict__ beta,
                   unsigned short* __restrict__ P) {
    const int i = blockIdx.x * 256 + threadIdx.x;   // [0, NV*32)
    const int r = i >> 5, c2 = (i & 31) * 2;
    float sc[2], sh[2];
#pragma unroll
    for (int j = 0; j < 2; ++j) {
        const int   c    = c2 + j;
        const float mu   = stats[c] * (1.f / NV);
        const float var  = fmaf(-mu, mu, stats[CC + c] * (1.f / NV));
        const float istd = rsqrtf(var + EPSV);
        sc[j] = gamma[c] * istd;
        sh[j] = fmaf(-mu, sc[j], beta[c]);
    }
    const float2 v = *(const float2*)(x + (size_t)r * CC + c2);
    const float y0 = fmaxf(fmaf(v.x, sc[0], sh[0]), 0.f);
    const float y1 = fmaxf(fmaf(v.y, sc[1], sh[1]), 0.f);
    unsigned short h0, l0, h1, l1;
    split2(y0, h0, l0);
    split2(y1, h1, l1);
    *(unsigned int*)(P + (size_t)r * 128 + c2)      = (unsigned)h0 | ((unsigned)h1 << 16);
    *(unsigned int*)(P + (size_t)r * 128 + 64 + c2) = (unsigned)l0 | ((unsigned)l1 << 16);
}

// ---------------------------------------------------------------------------
// BN + residual + ReLU, x (=d_out) updated in place.
// ---------------------------------------------------------------------------
__global__ __launch_bounds__(256)
void bn_res_relu(float* __restrict__ x, const float* __restrict__ feat,
                 const float* __restrict__ stats,
                 const float* __restrict__ gamma, const float* __restrict__ beta) {
    const int tid   = blockIdx.x * blockDim.x + threadIdx.x;
    const int total = NV * CC / 4;
    const int cbase = (tid * 4) & (CC - 1);
    float scale[4], shift[4];
#pragma unroll
    for (int j = 0; j < 4; ++j) {
        const int   c    = cbase + j;
        const float mu   = stats[c] * (1.f / NV);
        const float var  = fmaf(-mu, mu, stats[CC + c] * (1.f / NV));
        const float istd = rsqrtf(var + EPSV);
        scale[j] = gamma[c] * istd;
        shift[j] = fmaf(-mu, scale[j], beta[c]);
    }
    float4*       x4 = (float4*)x;
    const float4* f4 = (const float4*)feat;
    for (int i = tid; i < total; i += gridDim.x * blockDim.x) {
        float4 v = x4[i];
        const float4 fr = f4[i];
        v.x = fmaxf(fmaf(v.x, scale[0], shift[0]) + fr.x, 0.f);
        v.y = fmaxf(fmaf(v.y, scale[1], shift[1]) + fr.y, 0.f);
        v.z = fmaxf(fmaf(v.z, scale[2], shift[2]) + fr.z, 0.f);
        v.w = fmaxf(fmaf(v.w, scale[3], shift[3]) + fr.w, 0.f);
        x4[i] = v;
    }
}

// ---------------------------------------------------------------------------
extern "C" void kernel_launch(void* const* d_in, const int* in_sizes, int n_in,
                              void* d_out, int out_size, void* d_ws, size_t ws_size,
                              hipStream_t stream) {
    const float* features = (const float*)d_in[0];
    const float* W1       = (const float*)d_in[1];
    const float* gamma1   = (const float*)d_in[2];
    const float* beta1    = (const float*)d_in[3];
    const float* W2       = (const float*)d_in[4];
    const float* gamma2   = (const float*)d_in[5];
    const float* beta2    = (const float*)d_in[6];
    const int*   in_maps  = (const int*)d_in[7];
    const int*   out_maps = (const int*)d_in[8];

    float*          out   = (float*)d_out;                 // conv accumulator + final
    unsigned short* P     = (unsigned short*)d_ws;         // [N][128] bf16 hi/lo planes
    float*          stats = (float*)(P + (size_t)NV * 128);// 256 f32

    hipMemsetAsync(stats, 0, 256 * sizeof(float), stream);
    hipMemsetAsync(d_out, 0, (size_t)NV * CC * sizeof(float), stream);

    split_planes<<<12500, 256, 0, stream>>>(features, P);  // 12500*256 = NV*32 exact

    dim3 cgrid(MM / PPB, KK);                              // 125 x 27, no tail

    conv_mfma<<<cgrid, 256, 0, stream>>>(P, W1, in_maps, out_maps, out);
    bn_stats<<<400, 256, 0, stream>>>(out, stats);
    bn_relu_split<<<12500, 256, 0, stream>>>(out, stats, gamma1, beta1, P);

    hipMemsetAsync(d_out, 0, (size_t)NV * CC * sizeof(float), stream);
    conv_mfma<<<cgrid, 256, 0, stream>>>(P, W2, in_maps, out_maps, out);
    bn_stats<<<400, 256, 0, stream>>>(out, stats + 128);
    bn_res_relu<<<1024, 256, 0, stream>>>(out, features, stats + 128, gamma2, beta2);
}

// Round 6
// 645.408 us; speedup vs baseline: 1.4728x; 1.1649x over previous
//
#include <hip/hip_runtime.h>

typedef __attribute__((ext_vector_type(8))) short bf16x8;
typedef __attribute__((ext_vector_type(4))) float f32x4;

#define KK 27
#define MM 50000
#define NV 100000
#define CC 64
#define EPSV 1e-5f
#define PPB 400

// Dekker-style f32 -> bf16 hi (truncate, exact residual) + bf16 lo (RNE).
__device__ inline void split2(float x, unsigned short& h, unsigned short& l) {
    const unsigned u  = __float_as_uint(x);
    const unsigned hb = u & 0xFFFF0000u;
    h = (unsigned short)(hb >> 16);
    const float r = x - __uint_as_float(hb);      // exact
    const unsigned v = __float_as_uint(r);
    l = (unsigned short)((v + 0x7FFFu + ((v >> 16) & 1u)) >> 16);
}

__device__ inline unsigned short rne_bf16(float x) {
    const unsigned u = __float_as_uint(x);
    return (unsigned short)((u + 0x7FFFu + ((u >> 16) & 1u)) >> 16);
}

// ---------------------------------------------------------------------------
// features f32 [N][64] -> P [N][128] ushort: [0..63] bf16-hi, [64..127] bf16-lo
// ---------------------------------------------------------------------------
__global__ __launch_bounds__(256)
void split_planes(const float* __restrict__ x, unsigned short* __restrict__ P) {
    const int i = blockIdx.x * 256 + threadIdx.x;      // [0, NV*32)
    const int r = i >> 5, c2 = (i & 31) * 2;
    const float2 v = *(const float2*)(x + (size_t)r * CC + c2);
    unsigned short h0, l0, h1, l1;
    split2(v.x, h0, l0);
    split2(v.y, h1, l1);
    *(unsigned int*)(P + (size_t)r * 128 + c2)      = (unsigned)h0 | ((unsigned)h1 << 16);
    *(unsigned int*)(P + (size_t)r * 128 + 64 + c2) = (unsigned)l0 | ((unsigned)l1 << 16);
}

// ============================ CSR build (once) =============================
__global__ __launch_bounds__(256)
void csr_hist(const int* __restrict__ outm, int* __restrict__ cnt) {
    const int e = blockIdx.x * 256 + threadIdx.x;
    if (e < KK * MM) atomicAdd(&cnt[outm[e]], 1);
}

__global__ __launch_bounds__(1024)
void scan1(const int* __restrict__ cnt, int* __restrict__ off, int* __restrict__ bsum) {
    __shared__ int tmp[1024];
    const int t = threadIdx.x;
    const int i = blockIdx.x * 1024 + t;
    const int v = (i < NV) ? cnt[i] : 0;
    tmp[t] = v;
    __syncthreads();
    for (int d = 1; d < 1024; d <<= 1) {
        const int add = (t >= d) ? tmp[t - d] : 0;
        __syncthreads();
        tmp[t] += add;
        __syncthreads();
    }
    if (i < NV) off[i] = tmp[t] - v;        // exclusive within block
    if (t == 1023) bsum[blockIdx.x] = tmp[1023];
}

__global__ __launch_bounds__(128)
void scan2(int* __restrict__ bsum, int nb) {    // in-place exclusive, nb<=128
    __shared__ int tmp[128];
    const int t = threadIdx.x;
    const int v = (t < nb) ? bsum[t] : 0;
    tmp[t] = v;
    __syncthreads();
    for (int d = 1; d < 128; d <<= 1) {
        const int add = (t >= d) ? tmp[t - d] : 0;
        __syncthreads();
        tmp[t] += add;
        __syncthreads();
    }
    if (t < nb) bsum[t] = tmp[t] - v;
}

__global__ __launch_bounds__(256)
void scan3(int* __restrict__ off, const int* __restrict__ bsum) {
    const int i = blockIdx.x * 256 + threadIdx.x;
    if (i < NV) off[i] += bsum[i >> 10];
    if (i == 0) off[NV] = KK * MM;
}

__global__ __launch_bounds__(256)
void csr_fill(const int* __restrict__ outm, const int* __restrict__ off,
              int* __restrict__ cur, int* __restrict__ dst) {
    const int e = blockIdx.x * 256 + threadIdx.x;
    if (e >= KK * MM) return;
    const int row = outm[e];
    const int pos = atomicAdd(&cur[row], 1);
    dst[e] = off[row] + pos;
}

// ---------------------------------------------------------------------------
// MFMA GEMM, atomic-free: msgs[dst[e]] = bf16(f[inm[e]] @ W[k]) (plain stores)
// ---------------------------------------------------------------------------
#define MF(a, b, c) c = __builtin_amdgcn_mfma_f32_16x16x32_bf16(a, b, c, 0, 0, 0)

__global__ __launch_bounds__(256, 3)
void conv_gemm(const unsigned short* __restrict__ P, const float* __restrict__ W,
               const int* __restrict__ inm_all, const int* __restrict__ dst,
               unsigned short* __restrict__ msgs) {
    const int k   = blockIdx.y;
    const int L   = threadIdx.x & 63;
    const int wv  = threadIdx.x >> 6;
    const int g   = L >> 4;
    const int c16 = L & 15;

    __shared__ float lds[4352];

    {
        const float4* Wg  = (const float4*)(W + (size_t)k * CC * CC);
        float4*       Wl4 = (float4*)lds;
#pragma unroll
        for (int i = 0; i < 4; ++i)
            Wl4[threadIdx.x + 256 * i] = Wg[threadIdx.x + 256 * i];
    }
    __syncthreads();

    bf16x8 Wh[2][4], Wlo[2][4];
#pragma unroll
    for (int s = 0; s < 2; ++s)
#pragma unroll
        for (int t = 0; t < 4; ++t)
#pragma unroll
            for (int j = 0; j < 8; ++j) {
                const float w = lds[(g * 8 + j + 32 * s) * CC + 16 * t + c16];
                unsigned short h, lo;
                split2(w, h, lo);
                Wh[s][t][j]  = (short)h;
                Wlo[s][t][j] = (short)lo;
            }
    __syncthreads();

    float* ldsC = lds + wv * 1088;

    const int* inm = inm_all + (size_t)k * MM;
    const int pstart = blockIdx.x * PPB;
    const int pend   = min(MM, pstart + PPB);

    int base = pstart + wv * 16;
    if (base + 16 > pend) return;

    const unsigned short* rp = P + (size_t)inm[base + c16] * 128;
    bf16x8 ah0 = *(const bf16x8*)(rp +      g * 8);
    bf16x8 ah1 = *(const bf16x8*)(rp + 32 + g * 8);
    bf16x8 al0 = *(const bf16x8*)(rp + 64 + g * 8);
    bf16x8 al1 = *(const bf16x8*)(rp + 96 + g * 8);

    while (true) {
        const int  nbase = base + 64;
        const bool hasn  = (nbase + 16 <= pend);
        bf16x8 nh0, nh1, nl0, nl1;
        if (hasn) {
            const unsigned short* np = P + (size_t)inm[nbase + c16] * 128;
            nh0 = *(const bf16x8*)(np +      g * 8);
            nh1 = *(const bf16x8*)(np + 32 + g * 8);
            nl0 = *(const bf16x8*)(np + 64 + g * 8);
            nl1 = *(const bf16x8*)(np + 96 + g * 8);
        }

        f32x4 acc0 = {0.f, 0.f, 0.f, 0.f}, acc1 = acc0, acc2 = acc0, acc3 = acc0;
        MF(ah0, Wh[0][0], acc0); MF(ah0, Wh[0][1], acc1); MF(ah0, Wh[0][2], acc2); MF(ah0, Wh[0][3], acc3);
        MF(ah1, Wh[1][0], acc0); MF(ah1, Wh[1][1], acc1); MF(ah1, Wh[1][2], acc2); MF(ah1, Wh[1][3], acc3);
        MF(al0, Wh[0][0], acc0); MF(al0, Wh[0][1], acc1); MF(al0, Wh[0][2], acc2); MF(al0, Wh[0][3], acc3);
        MF(al1, Wh[1][0], acc0); MF(al1, Wh[1][1], acc1); MF(al1, Wh[1][2], acc2); MF(al1, Wh[1][3], acc3);
        MF(ah0, Wlo[0][0], acc0); MF(ah0, Wlo[0][1], acc1); MF(ah0, Wlo[0][2], acc2); MF(ah0, Wlo[0][3], acc3);
        MF(ah1, Wlo[1][0], acc0); MF(ah1, Wlo[1][1], acc1); MF(ah1, Wlo[1][2], acc2); MF(ah1, Wlo[1][3], acc3);

#pragma unroll
        for (int j = 0; j < 4; ++j) {
            ldsC[(g * 4 + j) * 68 +      c16] = acc0[j];
            ldsC[(g * 4 + j) * 68 + 16 + c16] = acc1[j];
            ldsC[(g * 4 + j) * 68 + 32 + c16] = acc2[j];
            ldsC[(g * 4 + j) * 68 + 48 + c16] = acc3[j];
        }
        const int e0 = k * MM + base;
#pragma unroll
        for (int r = 0; r < 16; ++r) {
            const int d = dst[e0 + r];
            msgs[(size_t)d * CC + L] = rne_bf16(ldsC[r * 68 + L]);  // 128B plain store
        }

        if (!hasn) break;
        base = nbase;
        ah0 = nh0; ah1 = nh1; al0 = nl0; al1 = nl1;
    }
}

// ---------------------------------------------------------------------------
// Gather-reduce: wave per output row, contiguous msg rows, f32 accumulate.
// ---------------------------------------------------------------------------
__global__ __launch_bounds__(256)
void csr_reduce(const unsigned short* __restrict__ msgs, const int* __restrict__ off,
                float* __restrict__ out) {
    const int L  = threadIdx.x & 63;
    const int wv = threadIdx.x >> 6;
    const int n  = blockIdx.x * 4 + wv;
    if (n >= NV) return;
    const int s = off[n], e = off[n + 1];
    float acc = 0.f;
    for (int i = s; i < e; ++i) {
        const unsigned short b = msgs[(size_t)i * CC + L];
        acc += __uint_as_float((unsigned)b << 16);
    }
    out[(size_t)n * CC + L] = acc;
}

// ============================ legacy atomic path ===========================
__global__ __launch_bounds__(256, 3)
void conv_mfma(const unsigned short* __restrict__ P, const float* __restrict__ W,
               const int* __restrict__ inm_all, const int* __restrict__ outm_all,
               float* __restrict__ out) {
    const int k   = blockIdx.y;
    const int L   = threadIdx.x & 63;
    const int wv  = threadIdx.x >> 6;
    const int g   = L >> 4;
    const int c16 = L & 15;

    __shared__ float lds[4352];
    {
        const float4* Wg  = (const float4*)(W + (size_t)k * CC * CC);
        float4*       Wl4 = (float4*)lds;
#pragma unroll
        for (int i = 0; i < 4; ++i)
            Wl4[threadIdx.x + 256 * i] = Wg[threadIdx.x + 256 * i];
    }
    __syncthreads();

    bf16x8 Wh[2][4], Wlo[2][4];
#pragma unroll
    for (int s = 0; s < 2; ++s)
#pragma unroll
        for (int t = 0; t < 4; ++t)
#pragma unroll
            for (int j = 0; j < 8; ++j) {
                const float w = lds[(g * 8 + j + 32 * s) * CC + 16 * t + c16];
                unsigned short h, lo;
                split2(w, h, lo);
                Wh[s][t][j]  = (short)h;
                Wlo[s][t][j] = (short)lo;
            }
    __syncthreads();

    float* ldsC = lds + wv * 1088;
    const int* inm  = inm_all  + (size_t)k * MM;
    const int* outm = outm_all + (size_t)k * MM;
    const int pstart = blockIdx.x * PPB;
    const int pend   = min(MM, pstart + PPB);

    int base = pstart + wv * 16;
    if (base + 16 > pend) return;

    const unsigned short* rp = P + (size_t)inm[base + c16] * 128;
    bf16x8 ah0 = *(const bf16x8*)(rp +      g * 8);
    bf16x8 ah1 = *(const bf16x8*)(rp + 32 + g * 8);
    bf16x8 al0 = *(const bf16x8*)(rp + 64 + g * 8);
    bf16x8 al1 = *(const bf16x8*)(rp + 96 + g * 8);

    while (true) {
        const int  nbase = base + 64;
        const bool hasn  = (nbase + 16 <= pend);
        bf16x8 nh0, nh1, nl0, nl1;
        if (hasn) {
            const unsigned short* np = P + (size_t)inm[nbase + c16] * 128;
            nh0 = *(const bf16x8*)(np +      g * 8);
            nh1 = *(const bf16x8*)(np + 32 + g * 8);
            nl0 = *(const bf16x8*)(np + 64 + g * 8);
            nl1 = *(const bf16x8*)(np + 96 + g * 8);
        }

        f32x4 acc0 = {0.f, 0.f, 0.f, 0.f}, acc1 = acc0, acc2 = acc0, acc3 = acc0;
        MF(ah0, Wh[0][0], acc0); MF(ah0, Wh[0][1], acc1); MF(ah0, Wh[0][2], acc2); MF(ah0, Wh[0][3], acc3);
        MF(ah1, Wh[1][0], acc0); MF(ah1, Wh[1][1], acc1); MF(ah1, Wh[1][2], acc2); MF(ah1, Wh[1][3], acc3);
        MF(al0, Wh[0][0], acc0); MF(al0, Wh[0][1], acc1); MF(al0, Wh[0][2], acc2); MF(al0, Wh[0][3], acc3);
        MF(al1, Wh[1][0], acc0); MF(al1, Wh[1][1], acc1); MF(al1, Wh[1][2], acc2); MF(al1, Wh[1][3], acc3);
        MF(ah0, Wlo[0][0], acc0); MF(ah0, Wlo[0][1], acc1); MF(ah0, Wlo[0][2], acc2); MF(ah0, Wlo[0][3], acc3);
        MF(ah1, Wlo[1][0], acc0); MF(ah1, Wlo[1][1], acc1); MF(ah1, Wlo[1][2], acc2); MF(ah1, Wlo[1][3], acc3);

#pragma unroll
        for (int j = 0; j < 4; ++j) {
            ldsC[(g * 4 + j) * 68 +      c16] = acc0[j];
            ldsC[(g * 4 + j) * 68 + 16 + c16] = acc1[j];
            ldsC[(g * 4 + j) * 68 + 32 + c16] = acc2[j];
            ldsC[(g * 4 + j) * 68 + 48 + c16] = acc3[j];
        }
#pragma unroll
        for (int r = 0; r < 16; ++r) {
            const int orow = outm[base + r];
            atomicAdd(&out[(size_t)orow * CC + L], ldsC[r * 68 + L]);
        }

        if (!hasn) break;
        base = nbase;
        ah0 = nh0; ah1 = nh1; al0 = nl0; al1 = nl1;
    }
}

// =============================== BN kernels ================================
__global__ __launch_bounds__(256)
void bn_stats(const float* __restrict__ x, float* __restrict__ stats) {
    const int c  = threadIdx.x & 63;
    const int rg = threadIdx.x >> 6;
    float s = 0.f, ss = 0.f;
    for (int r = blockIdx.x * 4 + rg; r < NV; r += gridDim.x * 4) {
        const float v = x[(size_t)r * CC + c];
        s += v;
        ss = fmaf(v, v, ss);
    }
    __shared__ float red[2][4][CC];
    red[0][rg][c] = s;
    red[1][rg][c] = ss;
    __syncthreads();
    if (threadIdx.x < CC) {
        const float ts  = red[0][0][c] + red[0][1][c] + red[0][2][c] + red[0][3][c];
        const float tss = red[1][0][c] + red[1][1][c] + red[1][2][c] + red[1][3][c];
        atomicAdd(&stats[c], ts);
        atomicAdd(&stats[CC + c], tss);
    }
}

__global__ __launch_bounds__(256)
void bn_relu_split(const float* __restrict__ x, const float* __restrict__ stats,
                   const float* __restrict__ gamma, const float* __restrict__ beta,
                   unsigned short* __restrict__ P) {
    const int i = blockIdx.x * 256 + threadIdx.x;
    const int r = i >> 5, c2 = (i & 31) * 2;
    float sc[2], sh[2];
#pragma unroll
    for (int j = 0; j < 2; ++j) {
        const int   c    = c2 + j;
        const float mu   = stats[c] * (1.f / NV);
        const float var  = fmaf(-mu, mu, stats[CC + c] * (1.f / NV));
        const float istd = rsqrtf(var + EPSV);
        sc[j] = gamma[c] * istd;
        sh[j] = fmaf(-mu, sc[j], beta[c]);
    }
    const float2 v = *(const float2*)(x + (size_t)r * CC + c2);
    const float y0 = fmaxf(fmaf(v.x, sc[0], sh[0]), 0.f);
    const float y1 = fmaxf(fmaf(v.y, sc[1], sh[1]), 0.f);
    unsigned short h0, l0, h1, l1;
    split2(y0, h0, l0);
    split2(y1, h1, l1);
    *(unsigned int*)(P + (size_t)r * 128 + c2)      = (unsigned)h0 | ((unsigned)h1 << 16);
    *(unsigned int*)(P + (size_t)r * 128 + 64 + c2) = (unsigned)l0 | ((unsigned)l1 << 16);
}

__global__ __launch_bounds__(256)
void bn_res_relu(float* __restrict__ x, const float* __restrict__ feat,
                 const float* __restrict__ stats,
                 const float* __restrict__ gamma, const float* __restrict__ beta) {
    const int tid   = blockIdx.x * blockDim.x + threadIdx.x;
    const int total = NV * CC / 4;
    const int cbase = (tid * 4) & (CC - 1);
    float scale[4], shift[4];
#pragma unroll
    for (int j = 0; j < 4; ++j) {
        const int   c    = cbase + j;
        const float mu   = stats[c] * (1.f / NV);
        const float var  = fmaf(-mu, mu, stats[CC + c] * (1.f / NV));
        const float istd = rsqrtf(var + EPSV);
        scale[j] = gamma[c] * istd;
        shift[j] = fmaf(-mu, scale[j], beta[c]);
    }
    float4*       x4 = (float4*)x;
    const float4* f4 = (const float4*)feat;
    for (int i = tid; i < total; i += gridDim.x * blockDim.x) {
        float4 v = x4[i];
        const float4 fr = f4[i];
        v.x = fmaxf(fmaf(v.x, scale[0], shift[0]) + fr.x, 0.f);
        v.y = fmaxf(fmaf(v.y, scale[1], shift[1]) + fr.y, 0.f);
        v.z = fmaxf(fmaf(v.z, scale[2], shift[2]) + fr.z, 0.f);
        v.w = fmaxf(fmaf(v.w, scale[3], shift[3]) + fr.w, 0.f);
        x4[i] = v;
    }
}

// ---------------------------------------------------------------------------
extern "C" void kernel_launch(void* const* d_in, const int* in_sizes, int n_in,
                              void* d_out, int out_size, void* d_ws, size_t ws_size,
                              hipStream_t stream) {
    const float* features = (const float*)d_in[0];
    const float* W1       = (const float*)d_in[1];
    const float* gamma1   = (const float*)d_in[2];
    const float* beta1    = (const float*)d_in[3];
    const float* W2       = (const float*)d_in[4];
    const float* gamma2   = (const float*)d_in[5];
    const float* beta2    = (const float*)d_in[6];
    const int*   in_maps  = (const int*)d_in[7];
    const int*   out_maps = (const int*)d_in[8];

    float* out = (float*)d_out;

    // ws layout
    unsigned short* P     = (unsigned short*)d_ws;           // NV*128 ushort
    float*          stats = (float*)(P + (size_t)NV * 128);  // 256 f32
    int*            cnt   = (int*)(stats + 256);             // NV
    int*            cur   = cnt + NV;                        // NV
    int*            off   = cur + NV;                        // NV+8
    int*            dst   = off + NV + 8;                    // KK*MM
    int*            bsum  = dst + KK * MM;                   // 256
    unsigned short* msgs  = (unsigned short*)(bsum + 256);   // KK*MM*64

    const size_t need = (size_t)((char*)(msgs + (size_t)KK * MM * CC) - (char*)d_ws);
    const bool csr = (ws_size >= need);

    dim3 cgrid(MM / PPB, KK);                                // 125 x 27

    if (csr) {
        // zero stats + cnt + cur in one contiguous memset
        hipMemsetAsync(stats, 0, (256 + 2 * NV) * sizeof(int), stream);

        split_planes<<<12500, 256, 0, stream>>>(features, P);

        // CSR build (maps shared by both convs)
        csr_hist<<<(KK * MM + 255) / 256, 256, 0, stream>>>(out_maps, cnt);
        const int nb = (NV + 1023) / 1024;                   // 98
        scan1<<<nb, 1024, 0, stream>>>(cnt, off, bsum);
        scan2<<<1, 128, 0, stream>>>(bsum, nb);
        scan3<<<(NV + 255) / 256, 256, 0, stream>>>(off, bsum);
        csr_fill<<<(KK * MM + 255) / 256, 256, 0, stream>>>(out_maps, off, cur, dst);

        conv_gemm<<<cgrid, 256, 0, stream>>>(P, W1, in_maps, dst, msgs);
        csr_reduce<<<NV / 4, 256, 0, stream>>>(msgs, off, out);
        bn_stats<<<400, 256, 0, stream>>>(out, stats);
        bn_relu_split<<<12500, 256, 0, stream>>>(out, stats, gamma1, beta1, P);

        conv_gemm<<<cgrid, 256, 0, stream>>>(P, W2, in_maps, dst, msgs);
        csr_reduce<<<NV / 4, 256, 0, stream>>>(msgs, off, out);
        bn_stats<<<400, 256, 0, stream>>>(out, stats + 128);
        bn_res_relu<<<1024, 256, 0, stream>>>(out, features, stats + 128, gamma2, beta2);
    } else {
        // legacy atomic path (proven): needs only P + stats
        hipMemsetAsync(stats, 0, 256 * sizeof(float), stream);
        hipMemsetAsync(d_out, 0, (size_t)NV * CC * sizeof(float), stream);

        split_planes<<<12500, 256, 0, stream>>>(features, P);

        conv_mfma<<<cgrid, 256, 0, stream>>>(P, W1, in_maps, out_maps, out);
        bn_stats<<<400, 256, 0, stream>>>(out, stats);
        bn_relu_split<<<12500, 256, 0, stream>>>(out, stats, gamma1, beta1, P);

        hipMemsetAsync(d_out, 0, (size_t)NV * CC * sizeof(float), stream);
        conv_mfma<<<cgrid, 256, 0, stream>>>(P, W2, in_maps, out_maps, out);
        bn_stats<<<400, 256, 0, stream>>>(out, stats + 128);
        bn_res_relu<<<1024, 256, 0, stream>>>(out, features, stats + 128, gamma2, beta2);
    }
}